// Round 1
// baseline (678.140 us; speedup 1.0000x reference)
//
#include <hip/hip_runtime.h>
#include <math.h>

#define BB 4
#define HH 8
#define LL 2048
#define DD 64
#define SK 40          // sample_k == u == 40 for L=2048, FACTOR=5
#define BH (BB*HH)

__device__ __forceinline__ float wave_reduce_sum(float v) {
    #pragma unroll
    for (int off = 32; off > 0; off >>= 1)
        v += __shfl_xor(v, off, 64);
    return v;
}

// Kernel 1: M[b,h,q] = max_s(q·K[idx[q,s]]) - sum_s(q·K[idx[q,s]])/L
// one wave per query position; lane = d
__global__ void compute_M_kernel(const float* __restrict__ Q,
                                 const float* __restrict__ K,
                                 const int* __restrict__ IDX,
                                 float* __restrict__ M) {
    int wave = blockIdx.x * 4 + (threadIdx.x >> 6);
    int lane = threadIdx.x & 63;
    int bh   = wave / LL;
    int qpos = wave % LL;
    float qv = Q[((size_t)bh * LL + qpos) * DD + lane];
    const float* Kbh = K + (size_t)bh * LL * DD;
    const int* idxrow = IDX + (size_t)qpos * SK;
    float mx = -INFINITY, sm = 0.f;
    for (int s = 0; s < SK; ++s) {
        int ks = idxrow[s];
        float kv = Kbh[(size_t)ks * DD + lane];
        float dot = wave_reduce_sum(qv * kv);
        mx = fmaxf(mx, dot);
        sm += dot;
    }
    if (lane == 0) M[(size_t)bh * LL + qpos] = mx - sm * (1.0f / (float)LL);
}

// Kernel 2: top-40 indices per (b,h) via 40 iterative argmax sweeps.
// Tie-break: smaller index (matches lax.top_k stability; ties ~impossible anyway).
__global__ void topk_kernel(const float* __restrict__ M, int* __restrict__ topk) {
    int bh  = blockIdx.x;
    int tid = threadIdx.x;
    __shared__ float sv[LL];
    __shared__ float rmax[256];
    __shared__ int   ridx[256];
    for (int i = tid; i < LL; i += 256) sv[i] = M[(size_t)bh * LL + i];
    __syncthreads();
    for (int it = 0; it < SK; ++it) {
        float best = -INFINITY; int bidx = LL;
        for (int i = tid; i < LL; i += 256) {
            float v = sv[i];
            if (v > best) { best = v; bidx = i; }
        }
        rmax[tid] = best; ridx[tid] = bidx;
        __syncthreads();
        for (int s = 128; s > 0; s >>= 1) {
            if (tid < s) {
                float vo = rmax[tid + s]; int io = ridx[tid + s];
                if (vo > rmax[tid] || (vo == rmax[tid] && io < ridx[tid])) {
                    rmax[tid] = vo; ridx[tid] = io;
                }
            }
            __syncthreads();
        }
        if (tid == 0) { topk[bh * SK + it] = ridx[0]; sv[ridx[0]] = -INFINITY; }
        __syncthreads();
    }
}

// Kernel 3: out[b,h,l,d] = cumsum_l V[b,h,:,d]. Block per (b,h),
// 1024 threads = 16 chunks (of 128) x 64 d-lanes, two-phase scan.
__global__ __launch_bounds__(1024) void cumsum_kernel(const float* __restrict__ V,
                                                      float* __restrict__ out) {
    int bh  = blockIdx.x;
    int tid = threadIdx.x;
    int c = tid >> 6, d = tid & 63;
    const int CL = LL / 16;  // 128
    size_t base = (size_t)bh * LL * DD;
    const float* Vb = V + base;
    float* Ob = out + base;
    int l0 = c * CL;
    float s = 0.f;
    for (int j = 0; j < CL; ++j) s += Vb[(size_t)(l0 + j) * DD + d];
    __shared__ float csum[16][DD];
    csum[c][d] = s;
    __syncthreads();
    float acc = 0.f;
    for (int cc = 0; cc < c; ++cc) acc += csum[cc][d];
    for (int j = 0; j < CL; ++j) {
        acc += Vb[(size_t)(l0 + j) * DD + d];
        Ob[(size_t)(l0 + j) * DD + d] = acc;
    }
}

// Kernel 4: for each selected row, causal softmax attention over keys [0..qpos],
// overwrite out[b,h,qpos,:]. One block (256 thr) per (bh,u).
__global__ void attn_kernel(const float* __restrict__ Q,
                            const float* __restrict__ K,
                            const float* __restrict__ V,
                            const int* __restrict__ topk,
                            float* __restrict__ out) {
    int bh  = blockIdx.x / SK;
    int u   = blockIdx.x % SK;
    int tid = threadIdx.x;
    int qpos = topk[bh * SK + u];
    int nk = qpos + 1;
    size_t base = (size_t)bh * LL * DD;
    __shared__ float qs[DD];
    __shared__ float sc[LL];
    __shared__ float red[256];
    __shared__ float part[4][DD];
    if (tid < DD) qs[tid] = Q[base + (size_t)qpos * DD + tid];
    __syncthreads();
    const float scale = 0.125f;  // 1/sqrt(64)
    for (int k = tid; k < nk; k += 256) {
        const float4* kr = (const float4*)(K + base + (size_t)k * DD);
        float dot = 0.f;
        #pragma unroll
        for (int j = 0; j < DD / 4; ++j) {
            float4 kv = kr[j];
            dot += kv.x * qs[4*j] + kv.y * qs[4*j+1] + kv.z * qs[4*j+2] + kv.w * qs[4*j+3];
        }
        sc[k] = dot * scale;
    }
    __syncthreads();
    // block max over sc[0..nk)
    float m = -INFINITY;
    for (int k = tid; k < nk; k += 256) m = fmaxf(m, sc[k]);
    red[tid] = m;
    __syncthreads();
    for (int s = 128; s > 0; s >>= 1) {
        if (tid < s) red[tid] = fmaxf(red[tid], red[tid + s]);
        __syncthreads();
    }
    m = red[0];
    __syncthreads();
    // exponentiate + block sum
    float lsum = 0.f;
    for (int k = tid; k < nk; k += 256) {
        float e = expf(sc[k] - m);
        sc[k] = e;
        lsum += e;
    }
    red[tid] = lsum;
    __syncthreads();
    for (int s = 128; s > 0; s >>= 1) {
        if (tid < s) red[tid] += red[tid + s];
        __syncthreads();
    }
    float linv = 1.0f / red[0];
    __syncthreads();
    // weighted V accumulation: 4 k-groups x 64 d-lanes
    int d = tid & 63, g = tid >> 6;
    float acc = 0.f;
    for (int k = g; k < nk; k += 4)
        acc += sc[k] * V[base + (size_t)k * DD + d];
    part[g][d] = acc;
    __syncthreads();
    if (g == 0) {
        float tot = part[0][d] + part[1][d] + part[2][d] + part[3][d];
        out[base + (size_t)qpos * DD + d] = tot * linv;
    }
}

extern "C" void kernel_launch(void* const* d_in, const int* in_sizes, int n_in,
                              void* d_out, int out_size, void* d_ws, size_t ws_size,
                              hipStream_t stream) {
    const float* Q   = (const float*)d_in[0];
    const float* K   = (const float*)d_in[1];
    const float* V   = (const float*)d_in[2];
    const int*   IDX = (const int*)d_in[3];
    float* out = (float*)d_out;

    float* M    = (float*)d_ws;                                   // BH*LL floats = 256 KB
    int*   topk = (int*)((char*)d_ws + (size_t)BH * LL * sizeof(float)); // BH*SK ints

    compute_M_kernel<<<(BB * HH * LL) / 4, 256, 0, stream>>>(Q, K, IDX, M);
    topk_kernel<<<BH, 256, 0, stream>>>(M, topk);
    cumsum_kernel<<<BH, 1024, 0, stream>>>(V, out);
    attn_kernel<<<BH * SK, 256, 0, stream>>>(Q, K, V, topk, out);
}

// Round 2
// 316.590 us; speedup vs baseline: 2.1420x; 2.1420x over previous
//
#include <hip/hip_runtime.h>
#include <math.h>

#define BB 4
#define HH 8
#define LL 2048
#define DD 64
#define SK 40            // sample_k == u == 40 for L=2048, FACTOR=5
#define BH (BB*HH)       // 32
#define TILE 256
#define NTILE (LL/TILE)  // 8

// ---------------------------------------------------------------------------
// Kernel 1: M[b,h,q] = max_s(q.K[idx[q,s]]) - sum_s(q.K[idx[q,s]])/L
// 4 threads per query (10 samples each), q row held in 16 float4 registers.
// blockIdx encodes bh&7 in low 3 bits -> all blocks of a bh on one XCD.
__global__ __launch_bounds__(256) void compute_M_kernel(
        const float* __restrict__ Q, const float* __restrict__ K,
        const int* __restrict__ IDX, float* __restrict__ M) {
    int x = blockIdx.x;               // 1024 blocks
    int bhLo = x & 7;
    int r = x >> 3;                   // [0,128)
    int bhHi = r & 3;
    int chunk = r >> 2;               // [0,32), 64 queries per chunk
    int bh = bhHi * 8 + bhLo;
    int tid = threadIdx.x;
    int qi = tid >> 2;                // query within chunk
    int part = tid & 3;               // sample quarter
    int qpos = chunk * 64 + qi;

    const float4* qrow = (const float4*)(Q + ((size_t)bh * LL + qpos) * DD);
    float4 q[16];
    #pragma unroll
    for (int j = 0; j < 16; ++j) q[j] = qrow[j];

    const float* Kbh = K + (size_t)bh * LL * DD;
    const int* idxrow = IDX + (size_t)qpos * SK;

    float mx = -INFINITY, sm = 0.f;
    for (int s = part * 10; s < part * 10 + 10; ++s) {
        int ks = idxrow[s];
        const float4* kr = (const float4*)(Kbh + (size_t)ks * DD);
        float d0 = 0.f, d1 = 0.f, d2 = 0.f, d3 = 0.f;
        #pragma unroll
        for (int j = 0; j < 16; j += 4) {
            float4 k0 = kr[j], k1 = kr[j+1], k2 = kr[j+2], k3 = kr[j+3];
            d0 += q[j].x*k0.x + q[j].y*k0.y + q[j].z*k0.z + q[j].w*k0.w;
            d1 += q[j+1].x*k1.x + q[j+1].y*k1.y + q[j+1].z*k1.z + q[j+1].w*k1.w;
            d2 += q[j+2].x*k2.x + q[j+2].y*k2.y + q[j+2].z*k2.z + q[j+2].w*k2.w;
            d3 += q[j+3].x*k3.x + q[j+3].y*k3.y + q[j+3].z*k3.z + q[j+3].w*k3.w;
        }
        float dot = (d0 + d1) + (d2 + d3);
        mx = fmaxf(mx, dot);
        sm += dot;
    }
    // combine the 4 sample-quarters (lanes 4*qi .. 4*qi+3, within one wave)
    mx = fmaxf(mx, __shfl_xor(mx, 1, 64));
    mx = fmaxf(mx, __shfl_xor(mx, 2, 64));
    sm += __shfl_xor(sm, 1, 64);
    sm += __shfl_xor(sm, 2, 64);
    if (part == 0) M[(size_t)bh * LL + qpos] = mx - sm * (1.0f / (float)LL);
}

// ---------------------------------------------------------------------------
// Kernel 2: top-40 per (b,h). 1024 threads; packed u64 (orderable-float, ~idx)
// argmax via wave shuffles; 2 barriers per sweep.
__device__ __forceinline__ unsigned long long ordkey(float v, int i) {
    unsigned u = __float_as_uint(v);
    u = (u & 0x80000000u) ? ~u : (u | 0x80000000u);
    return ((unsigned long long)u << 32) | (unsigned)(0xFFFFFFFFu - (unsigned)i);
}

__global__ __launch_bounds__(1024) void topk_kernel(const float* __restrict__ M,
                                                    int* __restrict__ topk) {
    int bh = blockIdx.x;
    int tid = threadIdx.x;
    __shared__ float sv[LL];
    __shared__ unsigned long long wbest[16];
    for (int i = tid; i < LL; i += 1024) sv[i] = M[(size_t)bh * LL + i];
    __syncthreads();
    int lane = tid & 63, wid = tid >> 6;
    for (int it = 0; it < SK; ++it) {
        unsigned long long k0 = ordkey(sv[tid], tid);
        unsigned long long k1 = ordkey(sv[tid + 1024], tid + 1024);
        unsigned long long kb = (k0 > k1) ? k0 : k1;
        #pragma unroll
        for (int off = 32; off > 0; off >>= 1) {
            unsigned long long ko = __shfl_xor(kb, off, 64);
            if (ko > kb) kb = ko;
        }
        if (lane == 0) wbest[wid] = kb;
        __syncthreads();
        if (tid == 0) {
            unsigned long long b = wbest[0];
            #pragma unroll
            for (int w = 1; w < 16; ++w) if (wbest[w] > b) b = wbest[w];
            int bi = (int)(0xFFFFFFFFu - (unsigned)(b & 0xFFFFFFFFull));
            topk[bh * SK + it] = bi;
            sv[bi] = -INFINITY;
        }
        __syncthreads();
    }
}

// ---------------------------------------------------------------------------
// Kernel 3a/3b: cumsum of V along L. 512 blocks (bh x 16 chunks of 128 rows),
// 256 thr = 64 d-lanes x 4 subgroups of 32 rows.
__global__ __launch_bounds__(256) void vsum_kernel(const float* __restrict__ V,
                                                   float* __restrict__ csum) {
    int x = blockIdx.x;               // 512
    int bhLo = x & 7, r = x >> 3;
    int bhHi = r & 3, c = r >> 2;     // c in [0,16)
    int bh = bhHi * 8 + bhLo;
    int tid = threadIdx.x;
    int d = tid & 63, sg = tid >> 6;
    size_t base = (size_t)bh * LL * DD;
    int row0 = c * 128 + sg * 32;
    float s = 0.f;
    for (int j = 0; j < 32; ++j) s += V[base + (size_t)(row0 + j) * DD + d];
    __shared__ float part[4][DD];
    part[sg][d] = s;
    __syncthreads();
    if (sg == 0)
        csum[((size_t)bh * 16 + c) * DD + d] = part[0][d] + part[1][d] + part[2][d] + part[3][d];
}

__global__ __launch_bounds__(256) void cumsum_kernel(const float* __restrict__ V,
                                                     const float* __restrict__ csum,
                                                     float* __restrict__ out) {
    int x = blockIdx.x;
    int bhLo = x & 7, r = x >> 3;
    int bhHi = r & 3, c = r >> 2;
    int bh = bhHi * 8 + bhLo;
    int tid = threadIdx.x;
    int d = tid & 63, sg = tid >> 6;
    size_t base = (size_t)bh * LL * DD;
    int row0 = c * 128 + sg * 32;
    float v[32];
    #pragma unroll
    for (int j = 0; j < 32; ++j) v[j] = V[base + (size_t)(row0 + j) * DD + d];
    float s = 0.f;
    #pragma unroll
    for (int j = 0; j < 32; ++j) s += v[j];
    __shared__ float part[4][DD];
    part[sg][d] = s;
    __syncthreads();
    float pre = 0.f;
    for (int cc = 0; cc < c; ++cc) pre += csum[((size_t)bh * 16 + cc) * DD + d];
    for (int ss = 0; ss < sg; ++ss) pre += part[ss][d];
    float acc = pre;
    #pragma unroll
    for (int j = 0; j < 32; ++j) {
        acc += v[j];
        out[base + (size_t)(row0 + j) * DD + d] = acc;
    }
}

// ---------------------------------------------------------------------------
// Kernel 4a: flash-style partials. One block per (bh,u,tile of 256 keys).
// blockIdx encoded so XCD = bh&7 and the 40 u-blocks sharing (bh,tile)'s
// K/V (128 KB) are consecutive -> L2 temporal reuse.
__global__ __launch_bounds__(256) void attn_part_kernel(
        const float* __restrict__ Q, const float* __restrict__ K,
        const float* __restrict__ V, const int* __restrict__ topk,
        float* __restrict__ ml, float* __restrict__ ov) {
    int x = blockIdx.x;               // 10240
    int bhLo = x & 7;
    int r = x >> 3;                   // [0,1280)
    int u = r % SK;
    int y = r / SK;                   // [0,32)
    int bhHi = y & 3;
    int tile = y >> 2;                // [0,8)
    int bh = bhHi * 8 + bhLo;
    int tid = threadIdx.x;

    int qpos = topk[bh * SK + u];
    int kstart = tile * TILE;
    if (kstart > qpos) return;
    int nk = min(TILE, qpos + 1 - kstart);
    size_t base = (size_t)bh * LL * DD;

    __shared__ float qs[DD];
    __shared__ float se[TILE];
    __shared__ float red[4];
    __shared__ float bc[1];
    __shared__ float opart[4][DD];

    if (tid < DD) qs[tid] = Q[base + (size_t)qpos * DD + tid];
    __syncthreads();

    float sc = -INFINITY;
    if (tid < nk) {
        const float4* kr = (const float4*)(K + base + (size_t)(kstart + tid) * DD);
        float d0 = 0.f, d1 = 0.f, d2 = 0.f, d3 = 0.f;
        #pragma unroll
        for (int j = 0; j < 16; j += 4) {
            float4 k0 = kr[j], k1 = kr[j+1], k2 = kr[j+2], k3 = kr[j+3];
            d0 += k0.x*qs[4*j+0] + k0.y*qs[4*j+1] + k0.z*qs[4*j+2] + k0.w*qs[4*j+3];
            d1 += k1.x*qs[4*j+4] + k1.y*qs[4*j+5] + k1.z*qs[4*j+6] + k1.w*qs[4*j+7];
            d2 += k2.x*qs[4*j+8] + k2.y*qs[4*j+9] + k2.z*qs[4*j+10] + k2.w*qs[4*j+11];
            d3 += k3.x*qs[4*j+12] + k3.y*qs[4*j+13] + k3.z*qs[4*j+14] + k3.w*qs[4*j+15];
        }
        sc = ((d0 + d1) + (d2 + d3)) * 0.125f;   // 1/sqrt(64)
    }
    int lane = tid & 63, wid = tid >> 6;
    // block max
    float wv = sc;
    #pragma unroll
    for (int off = 32; off > 0; off >>= 1) wv = fmaxf(wv, __shfl_xor(wv, off, 64));
    if (lane == 0) red[wid] = wv;
    __syncthreads();
    if (tid == 0) bc[0] = fmaxf(fmaxf(red[0], red[1]), fmaxf(red[2], red[3]));
    __syncthreads();
    float m = bc[0];
    float e = (tid < nk) ? expf(sc - m) : 0.f;
    se[tid] = e;
    // block sum
    float ws = e;
    #pragma unroll
    for (int off = 32; off > 0; off >>= 1) ws += __shfl_xor(ws, off, 64);
    if (lane == 0) red[wid] = ws;
    __syncthreads();

    int slot = (bh * SK + u) * NTILE + tile;
    if (tid == 0) {
        float l = red[0] + red[1] + red[2] + red[3];
        ml[(size_t)slot * 2]     = m;
        ml[(size_t)slot * 2 + 1] = l;
    }
    // weighted V partial: 64 d-lanes x 4 k-groups
    int d = tid & 63, g = tid >> 6;
    float acc = 0.f;
    for (int j = g; j < nk; j += 4)
        acc += se[j] * V[base + (size_t)(kstart + j) * DD + d];
    opart[g][d] = acc;
    __syncthreads();
    if (g == 0)
        ov[(size_t)slot * DD + d] = opart[0][d] + opart[1][d] + opart[2][d] + opart[3][d];
}

// Kernel 4b: combine tile partials, overwrite out rows. 1 wave per (bh,u).
__global__ __launch_bounds__(64) void attn_combine_kernel(
        const int* __restrict__ topk, const float* __restrict__ ml,
        const float* __restrict__ ov, float* __restrict__ out) {
    int bh = blockIdx.x / SK;
    int u  = blockIdx.x % SK;
    int d = threadIdx.x;
    int qpos = topk[bh * SK + u];
    int ntile = (qpos >> 8) + 1;
    int slot0 = (bh * SK + u) * NTILE;
    float gm = -INFINITY;
    for (int t = 0; t < ntile; ++t) gm = fmaxf(gm, ml[(size_t)(slot0 + t) * 2]);
    float o = 0.f, l = 0.f;
    for (int t = 0; t < ntile; ++t) {
        float w = expf(ml[(size_t)(slot0 + t) * 2] - gm);
        l += ml[(size_t)(slot0 + t) * 2 + 1] * w;
        o += ov[(size_t)(slot0 + t) * DD + d] * w;
    }
    out[(size_t)bh * LL * DD + (size_t)qpos * DD + d] = o / l;
}

// ---------------------------------------------------------------------------
extern "C" void kernel_launch(void* const* d_in, const int* in_sizes, int n_in,
                              void* d_out, int out_size, void* d_ws, size_t ws_size,
                              hipStream_t stream) {
    const float* Q   = (const float*)d_in[0];
    const float* K   = (const float*)d_in[1];
    const float* V   = (const float*)d_in[2];
    const int*   IDX = (const int*)d_in[3];
    float* out = (float*)d_out;

    char* ws = (char*)d_ws;
    float* M    = (float*)ws;                          ws += (size_t)BH * LL * sizeof(float);      // 256 KB
    int*   topk = (int*)ws;                            ws += ((size_t)BH * SK * sizeof(int) + 255) & ~255ull;
    float* csum = (float*)ws;                          ws += (size_t)BH * 16 * DD * sizeof(float); // 128 KB
    float* ml   = (float*)ws;                          ws += (size_t)BH * SK * NTILE * 2 * sizeof(float); // 80 KB
    float* ov   = (float*)ws;                          // BH*SK*NTILE*DD floats = 2.56 MB

    compute_M_kernel<<<1024, 256, 0, stream>>>(Q, K, IDX, M);
    topk_kernel<<<BH, 1024, 0, stream>>>(M, topk);
    vsum_kernel<<<512, 256, 0, stream>>>(V, csum);
    cumsum_kernel<<<512, 256, 0, stream>>>(V, csum, out);
    attn_part_kernel<<<BH * SK * NTILE, 256, 0, stream>>>(Q, K, V, topk, ml, ov);
    attn_combine_kernel<<<BH * SK, 64, 0, stream>>>(topk, ml, ov, out);
}

// Round 3
// 221.780 us; speedup vs baseline: 3.0577x; 1.4275x over previous
//
#include <hip/hip_runtime.h>
#include <math.h>

#define BB 4
#define HH 8
#define LL 2048
#define DD 64
#define SK 40            // sample_k == u == 40 for L=2048, FACTOR=5
#define BH (BB*HH)       // 32
#define TILE 256
#define NTILE (LL/TILE)  // 8

__device__ __forceinline__ unsigned long long shfl_xor_u64(unsigned long long v, int m) {
    unsigned lo = (unsigned)v, hi = (unsigned)(v >> 32);
    lo = __shfl_xor(lo, m, 64);
    hi = __shfl_xor(hi, m, 64);
    return ((unsigned long long)hi << 32) | lo;
}

__device__ __forceinline__ unsigned long long ordkey(float v, int i) {
    unsigned u = __float_as_uint(v);
    u = (u & 0x80000000u) ? ~u : (u | 0x80000000u);
    return ((unsigned long long)u << 32) | (unsigned)(0xFFFFFFFFu - (unsigned)i);
}

// ---------------------------------------------------------------------------
// Kernel 1: M[b,h,q] = max_s(q.K[idx[q,s]]) - sum_s(q.K[idx[q,s]])/L
// Lane layout: 16 lanes per query (lane&15 = float4 column chunk), 4 queries
// per wave, 16 queries per block. K row loads are coalesced 256 B segments.
__global__ __launch_bounds__(256) void compute_M_kernel(
        const float* __restrict__ Q, const float* __restrict__ K,
        const int* __restrict__ IDX, float* __restrict__ M) {
    int x = blockIdx.x;               // 4096 blocks
    int bhLo = x & 7;
    int r = x >> 3;                   // [0,512)
    int bhHi = r & 3;
    int chunk = r >> 2;               // [0,128), 16 queries each
    int bh = bhHi * 8 + bhLo;
    int qbase = chunk * 16;
    int tid = threadIdx.x;
    int w = tid >> 6, lane = tid & 63;
    int g = lane >> 4, ch = lane & 15;
    int qi = w * 4 + g;               // [0,16)
    int qpos = qbase + qi;

    __shared__ int sidx[16 * SK];
    for (int i = tid; i < 16 * SK; i += 256) sidx[i] = IDX[(size_t)qbase * SK + i];

    const float4* Q4 = (const float4*)Q;
    const float4* K4 = (const float4*)K;
    float4 q = Q4[((size_t)bh * LL + qpos) * 16 + ch];
    __syncthreads();

    size_t kb4 = (size_t)bh * LL * 16;
    float mx = -INFINITY, sm = 0.f;
    #pragma unroll 8
    for (int s = 0; s < SK; ++s) {
        int ks = sidx[qi * SK + s];
        float4 kv = K4[kb4 + (size_t)ks * 16 + ch];
        float p = q.x * kv.x + q.y * kv.y + q.z * kv.z + q.w * kv.w;
        p += __shfl_xor(p, 1, 64);
        p += __shfl_xor(p, 2, 64);
        p += __shfl_xor(p, 4, 64);
        p += __shfl_xor(p, 8, 64);
        mx = fmaxf(mx, p);
        sm += p;
    }
    if (ch == 0) M[(size_t)bh * LL + qpos] = mx - sm * (1.0f / (float)LL);
}

// ---------------------------------------------------------------------------
// Kernel 2: top-40 per (b,h), two-stage, nearly barrier-free.
// Stage A: each of 16 waves takes exact local top-40 of its 128 elements
// (register-resident, shuffle-only). Stage B: wave 0 selects top-40 of the
// 640 candidates. Top-40(2048) == Top-40(union of per-wave top-40s).
__global__ __launch_bounds__(1024) void topk_kernel(const float* __restrict__ M,
                                                    int* __restrict__ topk) {
    int bh = blockIdx.x;
    int tid = threadIdx.x;
    int lane = tid & 63, w = tid >> 6;
    __shared__ unsigned long long cand[16 * SK];

    int i0 = w * 128 + lane;
    int i1 = w * 128 + 64 + lane;
    float v0 = M[(size_t)bh * LL + i0];
    float v1 = M[(size_t)bh * LL + i1];
    for (int it = 0; it < SK; ++it) {
        unsigned long long k0 = ordkey(v0, i0);
        unsigned long long k1 = ordkey(v1, i1);
        unsigned long long kb = (k0 > k1) ? k0 : k1;
        #pragma unroll
        for (int off = 32; off > 0; off >>= 1) {
            unsigned long long ko = shfl_xor_u64(kb, off);
            if (ko > kb) kb = ko;
        }
        if (kb == k0) v0 = -INFINITY;
        else if (kb == k1) v1 = -INFINITY;
        if (lane == 0) cand[w * SK + it] = kb;
    }
    __syncthreads();
    if (w == 0) {
        unsigned long long loc[10];
        #pragma unroll
        for (int j = 0; j < 10; ++j) loc[j] = cand[lane * 10 + j];
        for (int it = 0; it < SK; ++it) {
            unsigned long long b = loc[0];
            int bj = 0;
            #pragma unroll
            for (int j = 1; j < 10; ++j)
                if (loc[j] > b) { b = loc[j]; bj = j; }
            unsigned long long bb = b;
            #pragma unroll
            for (int off = 32; off > 0; off >>= 1) {
                unsigned long long ko = shfl_xor_u64(bb, off);
                if (ko > bb) bb = ko;
            }
            if (bb == b) loc[bj] = 0ull;   // clear winner (unique idx => one lane)
            if (lane == 0)
                topk[bh * SK + it] = (int)(0xFFFFFFFFu - (unsigned)(bb & 0xFFFFFFFFull));
        }
    }
}

// ---------------------------------------------------------------------------
// Kernel 3a/3b: cumsum of V along L. 512 blocks (bh x 16 chunks of 128 rows).
__global__ __launch_bounds__(256) void vsum_kernel(const float* __restrict__ V,
                                                   float* __restrict__ csum) {
    int x = blockIdx.x;               // 512
    int bhLo = x & 7, r = x >> 3;
    int bhHi = r & 3, c = r >> 2;     // c in [0,16)
    int bh = bhHi * 8 + bhLo;
    int tid = threadIdx.x;
    int d = tid & 63, sg = tid >> 6;
    size_t base = (size_t)bh * LL * DD;
    int row0 = c * 128 + sg * 32;
    float s = 0.f;
    for (int j = 0; j < 32; ++j) s += V[base + (size_t)(row0 + j) * DD + d];
    __shared__ float part[4][DD];
    part[sg][d] = s;
    __syncthreads();
    if (sg == 0)
        csum[((size_t)bh * 16 + c) * DD + d] = part[0][d] + part[1][d] + part[2][d] + part[3][d];
}

__global__ __launch_bounds__(256) void cumsum_kernel(const float* __restrict__ V,
                                                     const float* __restrict__ csum,
                                                     float* __restrict__ out) {
    int x = blockIdx.x;
    int bhLo = x & 7, r = x >> 3;
    int bhHi = r & 3, c = r >> 2;
    int bh = bhHi * 8 + bhLo;
    int tid = threadIdx.x;
    int d = tid & 63, sg = tid >> 6;
    size_t base = (size_t)bh * LL * DD;
    int row0 = c * 128 + sg * 32;
    float v[32];
    #pragma unroll
    for (int j = 0; j < 32; ++j) v[j] = V[base + (size_t)(row0 + j) * DD + d];
    float s = 0.f;
    #pragma unroll
    for (int j = 0; j < 32; ++j) s += v[j];
    __shared__ float part[4][DD];
    part[sg][d] = s;
    __syncthreads();
    float pre = 0.f;
    for (int cc = 0; cc < c; ++cc) pre += csum[((size_t)bh * 16 + cc) * DD + d];
    for (int ss = 0; ss < sg; ++ss) pre += part[ss][d];
    float acc = pre;
    #pragma unroll
    for (int j = 0; j < 32; ++j) {
        acc += v[j];
        out[base + (size_t)(row0 + j) * DD + d] = acc;
    }
}

// ---------------------------------------------------------------------------
// Kernel 4a: flash-style partials, coalesced layout.
// Score phase: 16 lanes per key row (lane&15 = col chunk), 4 keys/wave-round.
// V phase: float4 columns x 16 key-groups.
__global__ __launch_bounds__(256) void attn_part_kernel(
        const float* __restrict__ Q, const float* __restrict__ K,
        const float* __restrict__ V, const int* __restrict__ topk,
        float* __restrict__ ml, float* __restrict__ ov) {
    int x = blockIdx.x;               // 10240
    int bhLo = x & 7;
    int r = x >> 3;                   // [0,1280)
    int u = r % SK;
    int y = r / SK;                   // [0,32)
    int bhHi = y & 3;
    int tile = y >> 2;                // [0,8)
    int bh = bhHi * 8 + bhLo;
    int tid = threadIdx.x;

    int qpos = topk[bh * SK + u];
    int kstart = tile * TILE;
    if (kstart > qpos) return;
    int nk = min(TILE, qpos + 1 - kstart);

    const float4* Q4 = (const float4*)Q;
    const float4* K4 = (const float4*)K;
    const float4* V4 = (const float4*)V;

    int w = tid >> 6, lane = tid & 63;
    int keysub = lane >> 4, ch = lane & 15;
    float4 qf = Q4[((size_t)bh * LL + qpos) * 16 + ch];

    __shared__ float se[TILE];
    __shared__ float red[4], red2[4];
    __shared__ float opart[16][16][4];

    size_t kb4 = ((size_t)bh * LL + kstart) * 16;
    #pragma unroll 4
    for (int rr = 0; rr < 16; ++rr) {
        int key = w * 64 + rr * 4 + keysub;
        float4 kv = K4[kb4 + (size_t)key * 16 + ch];
        float p = qf.x * kv.x + qf.y * kv.y + qf.z * kv.z + qf.w * kv.w;
        p += __shfl_xor(p, 1, 64);
        p += __shfl_xor(p, 2, 64);
        p += __shfl_xor(p, 4, 64);
        p += __shfl_xor(p, 8, 64);
        if (ch == 0) se[key] = (key < nk) ? p * 0.125f : -INFINITY;
    }
    __syncthreads();

    float sc = se[tid];
    float wv = sc;
    #pragma unroll
    for (int off = 32; off > 0; off >>= 1) wv = fmaxf(wv, __shfl_xor(wv, off, 64));
    if (lane == 0) red[w] = wv;
    __syncthreads();
    float m = fmaxf(fmaxf(red[0], red[1]), fmaxf(red[2], red[3]));
    float e = expf(sc - m);           // sc=-inf -> 0
    se[tid] = e;
    float ws = e;
    #pragma unroll
    for (int off = 32; off > 0; off >>= 1) ws += __shfl_xor(ws, off, 64);
    if (lane == 0) red2[w] = ws;
    __syncthreads();                  // also guarantees se[]=e visible

    int slot = (bh * SK + u) * NTILE + tile;
    if (tid == 0) {
        ml[(size_t)slot * 2]     = m;
        ml[(size_t)slot * 2 + 1] = red2[0] + red2[1] + red2[2] + red2[3];
    }

    int col4 = tid & 15, kg = tid >> 4;
    float ax = 0.f, ay = 0.f, az = 0.f, aw = 0.f;
    #pragma unroll 4
    for (int j = kg; j < nk; j += 16) {
        float sj = se[j];
        float4 vv = V4[((size_t)bh * LL + kstart + j) * 16 + col4];
        ax += sj * vv.x; ay += sj * vv.y; az += sj * vv.z; aw += sj * vv.w;
    }
    opart[kg][col4][0] = ax;
    opart[kg][col4][1] = ay;
    opart[kg][col4][2] = az;
    opart[kg][col4][3] = aw;
    __syncthreads();
    if (tid < DD) {
        int c4 = tid >> 2, cp = tid & 3;
        float s = 0.f;
        #pragma unroll
        for (int kg2 = 0; kg2 < 16; ++kg2) s += opart[kg2][c4][cp];
        ov[(size_t)slot * DD + tid] = s;
    }
}

// Kernel 4b: combine tile partials, overwrite out rows. 1 wave per (bh,u).
__global__ __launch_bounds__(64) void attn_combine_kernel(
        const int* __restrict__ topk, const float* __restrict__ ml,
        const float* __restrict__ ov, float* __restrict__ out) {
    int bh = blockIdx.x / SK;
    int u  = blockIdx.x % SK;
    int d = threadIdx.x;
    int qpos = topk[bh * SK + u];
    int ntile = (qpos >> 8) + 1;
    int slot0 = (bh * SK + u) * NTILE;
    float gm = -INFINITY;
    for (int t = 0; t < ntile; ++t) gm = fmaxf(gm, ml[(size_t)(slot0 + t) * 2]);
    float o = 0.f, l = 0.f;
    for (int t = 0; t < ntile; ++t) {
        float wgt = expf(ml[(size_t)(slot0 + t) * 2] - gm);
        l += ml[(size_t)(slot0 + t) * 2 + 1] * wgt;
        o += ov[(size_t)(slot0 + t) * DD + d] * wgt;
    }
    out[(size_t)bh * LL * DD + (size_t)qpos * DD + d] = o / l;
}

// ---------------------------------------------------------------------------
extern "C" void kernel_launch(void* const* d_in, const int* in_sizes, int n_in,
                              void* d_out, int out_size, void* d_ws, size_t ws_size,
                              hipStream_t stream) {
    const float* Q   = (const float*)d_in[0];
    const float* K   = (const float*)d_in[1];
    const float* V   = (const float*)d_in[2];
    const int*   IDX = (const int*)d_in[3];
    float* out = (float*)d_out;

    char* ws = (char*)d_ws;
    float* M    = (float*)ws;  ws += (size_t)BH * LL * sizeof(float);                 // 256 KB
    int*   topk = (int*)ws;    ws += ((size_t)BH * SK * sizeof(int) + 255) & ~255ull;
    float* csum = (float*)ws;  ws += (size_t)BH * 16 * DD * sizeof(float);            // 128 KB
    float* ml   = (float*)ws;  ws += (size_t)BH * SK * NTILE * 2 * sizeof(float);     // 80 KB
    float* ov   = (float*)ws;  // BH*SK*NTILE*DD floats = 2.56 MB

    compute_M_kernel<<<4096, 256, 0, stream>>>(Q, K, IDX, M);
    topk_kernel<<<BH, 1024, 0, stream>>>(M, topk);
    vsum_kernel<<<512, 256, 0, stream>>>(V, csum);
    cumsum_kernel<<<512, 256, 0, stream>>>(V, csum, out);
    attn_part_kernel<<<BH * SK * NTILE, 256, 0, stream>>>(Q, K, V, topk, ml, ov);
    attn_combine_kernel<<<BH * SK, 64, 0, stream>>>(topk, ml, ov, out);
}

// Round 4
// 187.763 us; speedup vs baseline: 3.6117x; 1.1812x over previous
//
#include <hip/hip_runtime.h>
#include <math.h>

#define BB 4
#define HH 8
#define LL 2048
#define DD 64
#define SK 40            // sample_k == u == 40 for L=2048, FACTOR=5
#define BH (BB*HH)       // 32
#define TILE 256
#define NTILE (LL/TILE)  // 8

__device__ __forceinline__ unsigned ordu(float v) {
    unsigned u = __float_as_uint(v);
    return (u & 0x80000000u) ? ~u : (u | 0x80000000u);
}

// ---------------------------------------------------------------------------
// Kernel 1: M[b,h,q] = max_s(q.K[idx[q,s]]) - sum_s(q.K[idx[q,s]])/L
// Lane layout: 16 lanes per query (lane&15 = float4 column chunk), 4 queries
// per wave, 16 queries per block. K row loads are coalesced 256 B segments.
__global__ __launch_bounds__(256) void compute_M_kernel(
        const float* __restrict__ Q, const float* __restrict__ K,
        const int* __restrict__ IDX, float* __restrict__ M) {
    int x = blockIdx.x;               // 4096 blocks
    int bhLo = x & 7;
    int r = x >> 3;                   // [0,512)
    int bhHi = r & 3;
    int chunk = r >> 2;               // [0,128), 16 queries each
    int bh = bhHi * 8 + bhLo;
    int qbase = chunk * 16;
    int tid = threadIdx.x;
    int w = tid >> 6, lane = tid & 63;
    int g = lane >> 4, ch = lane & 15;
    int qi = w * 4 + g;               // [0,16)
    int qpos = qbase + qi;

    __shared__ int sidx[16 * SK];
    for (int i = tid; i < 16 * SK; i += 256) sidx[i] = IDX[(size_t)qbase * SK + i];

    const float4* Q4 = (const float4*)Q;
    const float4* K4 = (const float4*)K;
    float4 q = Q4[((size_t)bh * LL + qpos) * 16 + ch];
    __syncthreads();

    size_t kb4 = (size_t)bh * LL * 16;
    float mx = -INFINITY, sm = 0.f;
    #pragma unroll 8
    for (int s = 0; s < SK; ++s) {
        int ks = sidx[qi * SK + s];
        float4 kv = K4[kb4 + (size_t)ks * 16 + ch];
        float p = q.x * kv.x + q.y * kv.y + q.z * kv.z + q.w * kv.w;
        p += __shfl_xor(p, 1, 64);
        p += __shfl_xor(p, 2, 64);
        p += __shfl_xor(p, 4, 64);
        p += __shfl_xor(p, 8, 64);
        mx = fmaxf(mx, p);
        sm += p;
    }
    if (ch == 0) M[(size_t)bh * LL + qpos] = mx - sm * (1.0f / (float)LL);
}

// ---------------------------------------------------------------------------
// Kernel 2: top-40 per (b,h) via 4-pass radix select (8 bits/pass) on the
// orderable-uint key, then unordered atomic emission. The reference only
// needs the index SET (scatter rows are independent & distinct), so emission
// order is irrelevant. Ties at threshold take smallest indices (= lax.top_k).
__global__ __launch_bounds__(1024) void topk_kernel(const float* __restrict__ M,
                                                    int* __restrict__ topk) {
    int bh = blockIdx.x;
    int tid = threadIdx.x;
    __shared__ unsigned hist[256];
    __shared__ unsigned bc_prefix, bc_need;
    __shared__ unsigned cnt_gt, cnt_eq;
    __shared__ int eqlist[128];

    unsigned v0 = ordu(M[(size_t)bh * LL + tid]);
    unsigned v1 = ordu(M[(size_t)bh * LL + tid + 1024]);

    unsigned prefix = 0, need = SK;
    #pragma unroll
    for (int pass = 0; pass < 4; ++pass) {
        const int s = 24 - 8 * pass;
        const unsigned maskHigh = (pass == 0) ? 0u : (0xFFFFFFFFu << (s + 8));
        if (tid < 256) hist[tid] = 0;
        __syncthreads();
        if (((v0 ^ prefix) & maskHigh) == 0) atomicAdd(&hist[(v0 >> s) & 0xFF], 1u);
        if (((v1 ^ prefix) & maskHigh) == 0) atomicAdd(&hist[(v1 >> s) & 0xFF], 1u);
        __syncthreads();
        if (tid < 256) {
            unsigned above = 0;
            for (int b = tid + 1; b < 256; ++b) above += hist[b];
            if (above < need && above + hist[tid] >= need) {
                bc_prefix = prefix | ((unsigned)tid << s);
                bc_need = need - above;
            }
        }
        __syncthreads();
        prefix = bc_prefix;
        need = bc_need;
        __syncthreads();
    }
    // prefix == orderable key of the 40th-largest value; need = #equals to take
    unsigned T = prefix;
    if (tid == 0) { cnt_gt = 0; cnt_eq = 0; }
    __syncthreads();
    if (v0 > T) { unsigned p = atomicAdd(&cnt_gt, 1u); topk[bh * SK + p] = tid; }
    else if (v0 == T) { unsigned p = atomicAdd(&cnt_eq, 1u); if (p < 128) eqlist[p] = tid; }
    if (v1 > T) { unsigned p = atomicAdd(&cnt_gt, 1u); topk[bh * SK + p] = tid + 1024; }
    else if (v1 == T) { unsigned p = atomicAdd(&cnt_eq, 1u); if (p < 128) eqlist[p] = tid + 1024; }
    __syncthreads();
    if (tid == 0) {
        int ne = (int)min(cnt_eq, 128u);
        unsigned base = cnt_gt;      // == SK - need
        for (unsigned r2 = 0; r2 < need; ++r2) {
            int bj = 0, bv = 0x7FFFFFFF;
            for (int j = 0; j < ne; ++j)
                if (eqlist[j] < bv) { bv = eqlist[j]; bj = j; }
            topk[bh * SK + base + r2] = bv;
            eqlist[bj] = 0x7FFFFFFF;
        }
    }
}

// ---------------------------------------------------------------------------
// Kernel 3a/3b: cumsum of V along L. 512 blocks (bh x 16 chunks of 128 rows).
__global__ __launch_bounds__(256) void vsum_kernel(const float* __restrict__ V,
                                                   float* __restrict__ csum) {
    int x = blockIdx.x;               // 512
    int bhLo = x & 7, r = x >> 3;
    int bhHi = r & 3, c = r >> 2;     // c in [0,16)
    int bh = bhHi * 8 + bhLo;
    int tid = threadIdx.x;
    int d = tid & 63, sg = tid >> 6;
    size_t base = (size_t)bh * LL * DD;
    int row0 = c * 128 + sg * 32;
    float s = 0.f;
    for (int j = 0; j < 32; ++j) s += V[base + (size_t)(row0 + j) * DD + d];
    __shared__ float part[4][DD];
    part[sg][d] = s;
    __syncthreads();
    if (sg == 0)
        csum[((size_t)bh * 16 + c) * DD + d] = part[0][d] + part[1][d] + part[2][d] + part[3][d];
}

__global__ __launch_bounds__(256) void cumsum_kernel(const float* __restrict__ V,
                                                     const float* __restrict__ csum,
                                                     float* __restrict__ out) {
    int x = blockIdx.x;
    int bhLo = x & 7, r = x >> 3;
    int bhHi = r & 3, c = r >> 2;
    int bh = bhHi * 8 + bhLo;
    int tid = threadIdx.x;
    int d = tid & 63, sg = tid >> 6;
    size_t base = (size_t)bh * LL * DD;
    int row0 = c * 128 + sg * 32;
    float v[32];
    #pragma unroll
    for (int j = 0; j < 32; ++j) v[j] = V[base + (size_t)(row0 + j) * DD + d];
    float s = 0.f;
    #pragma unroll
    for (int j = 0; j < 32; ++j) s += v[j];
    __shared__ float part[4][DD];
    part[sg][d] = s;
    __syncthreads();
    float pre = 0.f;
    for (int cc = 0; cc < c; ++cc) pre += csum[((size_t)bh * 16 + cc) * DD + d];
    for (int ss = 0; ss < sg; ++ss) pre += part[ss][d];
    float acc = pre;
    #pragma unroll
    for (int j = 0; j < 32; ++j) {
        acc += v[j];
        out[base + (size_t)(row0 + j) * DD + d] = acc;
    }
}

// ---------------------------------------------------------------------------
// Kernel 4a: flash-style partials, coalesced layout.
__global__ __launch_bounds__(256) void attn_part_kernel(
        const float* __restrict__ Q, const float* __restrict__ K,
        const float* __restrict__ V, const int* __restrict__ topk,
        float* __restrict__ ml, float* __restrict__ ov) {
    int x = blockIdx.x;               // 10240
    int bhLo = x & 7;
    int r = x >> 3;                   // [0,1280)
    int u = r % SK;
    int y = r / SK;                   // [0,32)
    int bhHi = y & 3;
    int tile = y >> 2;                // [0,8)
    int bh = bhHi * 8 + bhLo;
    int tid = threadIdx.x;

    int qpos = topk[bh * SK + u];
    int kstart = tile * TILE;
    if (kstart > qpos) return;
    int nk = min(TILE, qpos + 1 - kstart);

    const float4* Q4 = (const float4*)Q;
    const float4* K4 = (const float4*)K;
    const float4* V4 = (const float4*)V;

    int w = tid >> 6, lane = tid & 63;
    int keysub = lane >> 4, ch = lane & 15;
    float4 qf = Q4[((size_t)bh * LL + qpos) * 16 + ch];

    __shared__ float se[TILE];
    __shared__ float red[4], red2[4];
    __shared__ float opart[16][16][4];

    size_t kb4 = ((size_t)bh * LL + kstart) * 16;
    #pragma unroll 4
    for (int rr = 0; rr < 16; ++rr) {
        int key = w * 64 + rr * 4 + keysub;
        float4 kv = K4[kb4 + (size_t)key * 16 + ch];
        float p = qf.x * kv.x + qf.y * kv.y + qf.z * kv.z + qf.w * kv.w;
        p += __shfl_xor(p, 1, 64);
        p += __shfl_xor(p, 2, 64);
        p += __shfl_xor(p, 4, 64);
        p += __shfl_xor(p, 8, 64);
        if (ch == 0) se[key] = (key < nk) ? p * 0.125f : -INFINITY;
    }
    __syncthreads();

    float sc = se[tid];
    float wv = sc;
    #pragma unroll
    for (int off = 32; off > 0; off >>= 1) wv = fmaxf(wv, __shfl_xor(wv, off, 64));
    if (lane == 0) red[w] = wv;
    __syncthreads();
    float m = fmaxf(fmaxf(red[0], red[1]), fmaxf(red[2], red[3]));
    float e = expf(sc - m);           // sc=-inf -> 0
    se[tid] = e;
    float ws = e;
    #pragma unroll
    for (int off = 32; off > 0; off >>= 1) ws += __shfl_xor(ws, off, 64);
    if (lane == 0) red2[w] = ws;
    __syncthreads();                  // also guarantees se[]=e visible

    int slot = (bh * SK + u) * NTILE + tile;
    if (tid == 0) {
        ml[(size_t)slot * 2]     = m;
        ml[(size_t)slot * 2 + 1] = red2[0] + red2[1] + red2[2] + red2[3];
    }

    int col4 = tid & 15, kg = tid >> 4;
    float ax = 0.f, ay = 0.f, az = 0.f, aw = 0.f;
    #pragma unroll 4
    for (int j = kg; j < nk; j += 16) {
        float sj = se[j];
        float4 vv = V4[((size_t)bh * LL + kstart + j) * 16 + col4];
        ax += sj * vv.x; ay += sj * vv.y; az += sj * vv.z; aw += sj * vv.w;
    }
    opart[kg][col4][0] = ax;
    opart[kg][col4][1] = ay;
    opart[kg][col4][2] = az;
    opart[kg][col4][3] = aw;
    __syncthreads();
    if (tid < DD) {
        int c4 = tid >> 2, cp = tid & 3;
        float s = 0.f;
        #pragma unroll
        for (int kg2 = 0; kg2 < 16; ++kg2) s += opart[kg2][c4][cp];
        ov[(size_t)slot * DD + tid] = s;
    }
}

// Kernel 4b: combine tile partials, overwrite out rows. 1 wave per (bh,u).
__global__ __launch_bounds__(64) void attn_combine_kernel(
        const int* __restrict__ topk, const float* __restrict__ ml,
        const float* __restrict__ ov, float* __restrict__ out) {
    int bh = blockIdx.x / SK;
    int u  = blockIdx.x % SK;
    int d = threadIdx.x;
    int qpos = topk[bh * SK + u];
    int ntile = (qpos >> 8) + 1;
    int slot0 = (bh * SK + u) * NTILE;
    float gm = -INFINITY;
    for (int t = 0; t < ntile; ++t) gm = fmaxf(gm, ml[(size_t)(slot0 + t) * 2]);
    float o = 0.f, l = 0.f;
    for (int t = 0; t < ntile; ++t) {
        float wgt = expf(ml[(size_t)(slot0 + t) * 2] - gm);
        l += ml[(size_t)(slot0 + t) * 2 + 1] * wgt;
        o += ov[(size_t)(slot0 + t) * DD + d] * wgt;
    }
    out[(size_t)bh * LL * DD + (size_t)qpos * DD + d] = o / l;
}

// ---------------------------------------------------------------------------
extern "C" void kernel_launch(void* const* d_in, const int* in_sizes, int n_in,
                              void* d_out, int out_size, void* d_ws, size_t ws_size,
                              hipStream_t stream) {
    const float* Q   = (const float*)d_in[0];
    const float* K   = (const float*)d_in[1];
    const float* V   = (const float*)d_in[2];
    const int*   IDX = (const int*)d_in[3];
    float* out = (float*)d_out;

    char* ws = (char*)d_ws;
    float* M    = (float*)ws;  ws += (size_t)BH * LL * sizeof(float);                 // 256 KB
    int*   topk = (int*)ws;    ws += ((size_t)BH * SK * sizeof(int) + 255) & ~255ull;
    float* csum = (float*)ws;  ws += (size_t)BH * 16 * DD * sizeof(float);            // 128 KB
    float* ml   = (float*)ws;  ws += (size_t)BH * SK * NTILE * 2 * sizeof(float);     // 80 KB
    float* ov   = (float*)ws;  // BH*SK*NTILE*DD floats = 2.56 MB

    compute_M_kernel<<<4096, 256, 0, stream>>>(Q, K, IDX, M);
    topk_kernel<<<BH, 1024, 0, stream>>>(M, topk);
    vsum_kernel<<<512, 256, 0, stream>>>(V, csum);
    cumsum_kernel<<<512, 256, 0, stream>>>(V, csum, out);
    attn_part_kernel<<<BH * SK * NTILE, 256, 0, stream>>>(Q, K, V, topk, ml, ov);
    attn_combine_kernel<<<BH * SK, 64, 0, stream>>>(topk, ml, ov, out);
}

// Round 5
// 167.815 us; speedup vs baseline: 4.0410x; 1.1189x over previous
//
#include <hip/hip_runtime.h>
#include <math.h>

#define BB 4
#define HH 8
#define LL 2048
#define DD 64
#define SK 40            // sample_k == u == 40 for L=2048, FACTOR=5
#define BH (BB*HH)       // 32
#define TILE 256
#define NTILE (LL/TILE)  // 8

__device__ __forceinline__ unsigned ordu(float v) {
    unsigned u = __float_as_uint(v);
    return (u & 0x80000000u) ? ~u : (u | 0x80000000u);
}

// ---------------------------------------------------------------------------
// Kernel 1: M[b,h,q] = max_s(q.K[idx[q,s]]) - sum_s(q.K[idx[q,s]])/L
// Lane layout: 4 lanes per query (lane&3 = 16-float chunk), 16 queries/wave,
// 64 queries/block. Per sample: 4 loads (64B-contiguous per 4-lane group),
// 16 FMAs, 2-deep shuffle reduce.
__global__ __launch_bounds__(256) void compute_M_kernel(
        const float* __restrict__ Q, const float* __restrict__ K,
        const int* __restrict__ IDX, float* __restrict__ M) {
    int x = blockIdx.x;               // 1024 blocks
    int bhLo = x & 7;
    int r = x >> 3;                   // [0,128)
    int bhHi = r & 3;
    int chunk = r >> 2;               // [0,32), 64 queries each
    int bh = bhHi * 8 + bhLo;
    int qbase = chunk * 64;
    int tid = threadIdx.x;
    int w = tid >> 6, lane = tid & 63;
    int qw = lane >> 2, c = lane & 3;
    int qi = w * 16 + qw;             // [0,64)
    int qpos = qbase + qi;

    __shared__ int sidx[64 * SK];     // 10 KB
    for (int i = tid; i < 64 * SK; i += 256) sidx[i] = IDX[(size_t)qbase * SK + i];

    const float4* Q4 = (const float4*)Q;
    const float4* K4 = (const float4*)K;
    float4 qreg[4];
    #pragma unroll
    for (int j = 0; j < 4; ++j)
        qreg[j] = Q4[((size_t)bh * LL + qpos) * 16 + j * 4 + c];
    __syncthreads();

    size_t kb4 = (size_t)bh * LL * 16;
    float mx = -INFINITY, sm = 0.f;
    #pragma unroll 8
    for (int s = 0; s < SK; ++s) {
        int ks = sidx[qi * SK + s];
        const float4* kr = K4 + kb4 + (size_t)ks * 16;
        float p = 0.f;
        #pragma unroll
        for (int j = 0; j < 4; ++j) {
            float4 kv = kr[j * 4 + c];
            p += qreg[j].x * kv.x + qreg[j].y * kv.y + qreg[j].z * kv.z + qreg[j].w * kv.w;
        }
        p += __shfl_xor(p, 1, 64);
        p += __shfl_xor(p, 2, 64);
        mx = fmaxf(mx, p);
        sm += p;
    }
    if (c == 0) M[(size_t)bh * LL + qpos] = mx - sm * (1.0f / (float)LL);
}

// ---------------------------------------------------------------------------
// Kernel 2: top-40 per (b,h) via 4-pass radix select (8 bits/pass) on the
// orderable-uint key, then unordered atomic emission (index SET is all that
// matters). Ties at threshold take smallest indices (= lax.top_k).
__global__ __launch_bounds__(1024) void topk_kernel(const float* __restrict__ M,
                                                    int* __restrict__ topk) {
    int bh = blockIdx.x;
    int tid = threadIdx.x;
    __shared__ unsigned hist[256];
    __shared__ unsigned bc_prefix, bc_need;
    __shared__ unsigned cnt_gt, cnt_eq;
    __shared__ int eqlist[128];

    unsigned v0 = ordu(M[(size_t)bh * LL + tid]);
    unsigned v1 = ordu(M[(size_t)bh * LL + tid + 1024]);

    unsigned prefix = 0, need = SK;
    #pragma unroll
    for (int pass = 0; pass < 4; ++pass) {
        const int s = 24 - 8 * pass;
        const unsigned maskHigh = (pass == 0) ? 0u : (0xFFFFFFFFu << (s + 8));
        if (tid < 256) hist[tid] = 0;
        __syncthreads();
        if (((v0 ^ prefix) & maskHigh) == 0) atomicAdd(&hist[(v0 >> s) & 0xFF], 1u);
        if (((v1 ^ prefix) & maskHigh) == 0) atomicAdd(&hist[(v1 >> s) & 0xFF], 1u);
        __syncthreads();
        if (tid < 256) {
            unsigned above = 0;
            for (int b = tid + 1; b < 256; ++b) above += hist[b];
            if (above < need && above + hist[tid] >= need) {
                bc_prefix = prefix | ((unsigned)tid << s);
                bc_need = need - above;
            }
        }
        __syncthreads();
        prefix = bc_prefix;
        need = bc_need;
        __syncthreads();
    }
    unsigned T = prefix;
    if (tid == 0) { cnt_gt = 0; cnt_eq = 0; }
    __syncthreads();
    if (v0 > T) { unsigned p = atomicAdd(&cnt_gt, 1u); topk[bh * SK + p] = tid; }
    else if (v0 == T) { unsigned p = atomicAdd(&cnt_eq, 1u); if (p < 128) eqlist[p] = tid; }
    if (v1 > T) { unsigned p = atomicAdd(&cnt_gt, 1u); topk[bh * SK + p] = tid + 1024; }
    else if (v1 == T) { unsigned p = atomicAdd(&cnt_eq, 1u); if (p < 128) eqlist[p] = tid + 1024; }
    __syncthreads();
    if (tid == 0) {
        int ne = (int)min(cnt_eq, 128u);
        unsigned base = cnt_gt;
        for (unsigned r2 = 0; r2 < need; ++r2) {
            int bj = 0, bv = 0x7FFFFFFF;
            for (int j = 0; j < ne; ++j)
                if (eqlist[j] < bv) { bv = eqlist[j]; bj = j; }
            topk[bh * SK + base + r2] = bv;
            eqlist[bj] = 0x7FFFFFFF;
        }
    }
}

// ---------------------------------------------------------------------------
// Kernel 3a/3b: cumsum of V along L. 512 blocks (bh x 16 chunks of 128 rows).
__global__ __launch_bounds__(256) void vsum_kernel(const float* __restrict__ V,
                                                   float* __restrict__ csum) {
    int x = blockIdx.x;               // 512
    int bhLo = x & 7, r = x >> 3;
    int bhHi = r & 3, c = r >> 2;     // c in [0,16)
    int bh = bhHi * 8 + bhLo;
    int tid = threadIdx.x;
    int d = tid & 63, sg = tid >> 6;
    size_t base = (size_t)bh * LL * DD;
    int row0 = c * 128 + sg * 32;
    float s = 0.f;
    for (int j = 0; j < 32; ++j) s += V[base + (size_t)(row0 + j) * DD + d];
    __shared__ float part[4][DD];
    part[sg][d] = s;
    __syncthreads();
    if (sg == 0)
        csum[((size_t)bh * 16 + c) * DD + d] = part[0][d] + part[1][d] + part[2][d] + part[3][d];
}

__global__ __launch_bounds__(256) void cumsum_kernel(const float* __restrict__ V,
                                                     const float* __restrict__ csum,
                                                     float* __restrict__ out) {
    int x = blockIdx.x;
    int bhLo = x & 7, r = x >> 3;
    int bhHi = r & 3, c = r >> 2;
    int bh = bhHi * 8 + bhLo;
    int tid = threadIdx.x;
    int d = tid & 63, sg = tid >> 6;
    size_t base = (size_t)bh * LL * DD;
    int row0 = c * 128 + sg * 32;
    float v[32];
    #pragma unroll
    for (int j = 0; j < 32; ++j) v[j] = V[base + (size_t)(row0 + j) * DD + d];
    float s = 0.f;
    #pragma unroll
    for (int j = 0; j < 32; ++j) s += v[j];
    __shared__ float part[4][DD];
    part[sg][d] = s;
    __syncthreads();
    float pre = 0.f;
    for (int cc = 0; cc < c; ++cc) pre += csum[((size_t)bh * 16 + cc) * DD + d];
    for (int ss = 0; ss < sg; ++ss) pre += part[ss][d];
    float acc = pre;
    #pragma unroll
    for (int j = 0; j < 32; ++j) {
        acc += v[j];
        out[base + (size_t)(row0 + j) * DD + d] = acc;
    }
}

// ---------------------------------------------------------------------------
// Kernel 4a: flash-style partials. Score phase: 4 lanes/key, 16 keys/wave-
// round, 4 rounds; 2-deep shuffle reduce. V phase: float4 cols x 16 k-groups.
__global__ __launch_bounds__(256) void attn_part_kernel(
        const float* __restrict__ Q, const float* __restrict__ K,
        const float* __restrict__ V, const int* __restrict__ topk,
        float* __restrict__ ml, float* __restrict__ ov) {
    int x = blockIdx.x;               // 10240
    int bhLo = x & 7;
    int r = x >> 3;                   // [0,1280)
    int u = r % SK;
    int y = r / SK;                   // [0,32)
    int bhHi = y & 3;
    int tile = y >> 2;                // [0,8)
    int bh = bhHi * 8 + bhLo;
    int tid = threadIdx.x;

    int qpos = topk[bh * SK + u];
    int kstart = tile * TILE;
    if (kstart > qpos) return;
    int nk = min(TILE, qpos + 1 - kstart);

    const float4* Q4 = (const float4*)Q;
    const float4* K4 = (const float4*)K;
    const float4* V4 = (const float4*)V;

    int w = tid >> 6, lane = tid & 63;
    int kw = lane >> 2, c = lane & 3;
    float4 qreg[4];
    #pragma unroll
    for (int j = 0; j < 4; ++j)
        qreg[j] = Q4[((size_t)bh * LL + qpos) * 16 + j * 4 + c];

    __shared__ float se[TILE];
    __shared__ float red[4], red2[4];
    __shared__ float opart[16][16][4];

    size_t kb4 = ((size_t)bh * LL + kstart) * 16;
    #pragma unroll
    for (int rr = 0; rr < 4; ++rr) {
        int key = w * 64 + rr * 16 + kw;
        const float4* kr = K4 + kb4 + (size_t)key * 16;
        float p = 0.f;
        #pragma unroll
        for (int j = 0; j < 4; ++j) {
            float4 kv = kr[j * 4 + c];
            p += qreg[j].x * kv.x + qreg[j].y * kv.y + qreg[j].z * kv.z + qreg[j].w * kv.w;
        }
        p += __shfl_xor(p, 1, 64);
        p += __shfl_xor(p, 2, 64);
        if (c == 0) se[key] = (key < nk) ? p * 0.125f : -INFINITY;
    }
    __syncthreads();

    float sc = se[tid];
    float wv = sc;
    #pragma unroll
    for (int off = 32; off > 0; off >>= 1) wv = fmaxf(wv, __shfl_xor(wv, off, 64));
    if (lane == 0) red[w] = wv;
    __syncthreads();
    float m = fmaxf(fmaxf(red[0], red[1]), fmaxf(red[2], red[3]));
    float e = expf(sc - m);           // sc=-inf -> 0
    se[tid] = e;
    float ws = e;
    #pragma unroll
    for (int off = 32; off > 0; off >>= 1) ws += __shfl_xor(ws, off, 64);
    if (lane == 0) red2[w] = ws;
    __syncthreads();                  // also guarantees se[]=e visible

    int slot = (bh * SK + u) * NTILE + tile;
    if (tid == 0) {
        ml[(size_t)slot * 2]     = m;
        ml[(size_t)slot * 2 + 1] = red2[0] + red2[1] + red2[2] + red2[3];
    }

    int col4 = tid & 15, kg = tid >> 4;
    float ax = 0.f, ay = 0.f, az = 0.f, aw = 0.f;
    #pragma unroll 4
    for (int j = kg; j < nk; j += 16) {
        float sj = se[j];
        float4 vv = V4[((size_t)bh * LL + kstart + j) * 16 + col4];
        ax += sj * vv.x; ay += sj * vv.y; az += sj * vv.z; aw += sj * vv.w;
    }
    opart[kg][col4][0] = ax;
    opart[kg][col4][1] = ay;
    opart[kg][col4][2] = az;
    opart[kg][col4][3] = aw;
    __syncthreads();
    if (tid < DD) {
        int c4 = tid >> 2, cp = tid & 3;
        float s = 0.f;
        #pragma unroll
        for (int kg2 = 0; kg2 < 16; ++kg2) s += opart[kg2][c4][cp];
        ov[(size_t)slot * DD + tid] = s;
    }
}

// Kernel 4b: combine tile partials, overwrite out rows. 1 wave per (bh,u).
__global__ __launch_bounds__(64) void attn_combine_kernel(
        const int* __restrict__ topk, const float* __restrict__ ml,
        const float* __restrict__ ov, float* __restrict__ out) {
    int bh = blockIdx.x / SK;
    int u  = blockIdx.x % SK;
    int d = threadIdx.x;
    int qpos = topk[bh * SK + u];
    int ntile = (qpos >> 8) + 1;
    int slot0 = (bh * SK + u) * NTILE;
    float gm = -INFINITY;
    for (int t = 0; t < ntile; ++t) gm = fmaxf(gm, ml[(size_t)(slot0 + t) * 2]);
    float o = 0.f, l = 0.f;
    for (int t = 0; t < ntile; ++t) {
        float wgt = expf(ml[(size_t)(slot0 + t) * 2] - gm);
        l += ml[(size_t)(slot0 + t) * 2 + 1] * wgt;
        o += ov[(size_t)(slot0 + t) * DD + d] * wgt;
    }
    out[(size_t)bh * LL * DD + (size_t)qpos * DD + d] = o / l;
}

// ---------------------------------------------------------------------------
extern "C" void kernel_launch(void* const* d_in, const int* in_sizes, int n_in,
                              void* d_out, int out_size, void* d_ws, size_t ws_size,
                              hipStream_t stream) {
    const float* Q   = (const float*)d_in[0];
    const float* K   = (const float*)d_in[1];
    const float* V   = (const float*)d_in[2];
    const int*   IDX = (const int*)d_in[3];
    float* out = (float*)d_out;

    char* ws = (char*)d_ws;
    float* M    = (float*)ws;  ws += (size_t)BH * LL * sizeof(float);                 // 256 KB
    int*   topk = (int*)ws;    ws += ((size_t)BH * SK * sizeof(int) + 255) & ~255ull;
    float* csum = (float*)ws;  ws += (size_t)BH * 16 * DD * sizeof(float);            // 128 KB
    float* ml   = (float*)ws;  ws += (size_t)BH * SK * NTILE * 2 * sizeof(float);     // 80 KB
    float* ov   = (float*)ws;  // BH*SK*NTILE*DD floats = 2.56 MB

    compute_M_kernel<<<1024, 256, 0, stream>>>(Q, K, IDX, M);
    topk_kernel<<<BH, 1024, 0, stream>>>(M, topk);
    vsum_kernel<<<512, 256, 0, stream>>>(V, csum);
    cumsum_kernel<<<512, 256, 0, stream>>>(V, csum, out);
    attn_part_kernel<<<BH * SK * NTILE, 256, 0, stream>>>(Q, K, V, topk, ml, ov);
    attn_combine_kernel<<<BH * SK, 64, 0, stream>>>(topk, ml, ov, out);
}

// Round 6
// 166.514 us; speedup vs baseline: 4.0726x; 1.0078x over previous
//
#include <hip/hip_runtime.h>
#include <math.h>

#define BB 4
#define HH 8
#define LL 2048
#define DD 64
#define SK 40            // sample_k == u == 40 for L=2048, FACTOR=5
#define BH (BB*HH)       // 32

__device__ __forceinline__ unsigned ordu(float v) {
    unsigned u = __float_as_uint(v);
    return (u & 0x80000000u) ? ~u : (u | 0x80000000u);
}

// ---------------------------------------------------------------------------
// Stage 1: blocks [0,1024) compute M; blocks [1024,1536) compute V chunk sums.
__global__ __launch_bounds__(256) void stage1_kernel(
        const float* __restrict__ Q, const float* __restrict__ K,
        const float* __restrict__ V, const int* __restrict__ IDX,
        float* __restrict__ M, float* __restrict__ csum) {
    int tid = threadIdx.x;
    if (blockIdx.x < 1024) {
        // ----- compute_M: 4 lanes/query, 16 queries/wave, 64 queries/block
        int x = blockIdx.x;
        int bhLo = x & 7;
        int r = x >> 3;                   // [0,128)
        int bhHi = r & 3;
        int chunk = r >> 2;               // [0,32)
        int bh = bhHi * 8 + bhLo;
        int qbase = chunk * 64;
        int w = tid >> 6, lane = tid & 63;
        int qw = lane >> 2, c = lane & 3;
        int qi = w * 16 + qw;
        int qpos = qbase + qi;

        __shared__ int sidx[64 * SK];     // 10 KB
        for (int i = tid; i < 64 * SK; i += 256) sidx[i] = IDX[(size_t)qbase * SK + i];

        const float4* Q4 = (const float4*)Q;
        const float4* K4 = (const float4*)K;
        float4 qreg[4];
        #pragma unroll
        for (int j = 0; j < 4; ++j)
            qreg[j] = Q4[((size_t)bh * LL + qpos) * 16 + j * 4 + c];
        __syncthreads();

        size_t kb4 = (size_t)bh * LL * 16;
        float mx = -INFINITY, sm = 0.f;
        #pragma unroll 8
        for (int s = 0; s < SK; ++s) {
            int ks = sidx[qi * SK + s];
            const float4* kr = K4 + kb4 + (size_t)ks * 16;
            float p = 0.f;
            #pragma unroll
            for (int j = 0; j < 4; ++j) {
                float4 kv = kr[j * 4 + c];
                p += qreg[j].x * kv.x + qreg[j].y * kv.y + qreg[j].z * kv.z + qreg[j].w * kv.w;
            }
            p += __shfl_xor(p, 1, 64);
            p += __shfl_xor(p, 2, 64);
            mx = fmaxf(mx, p);
            sm += p;
        }
        if (c == 0) M[(size_t)bh * LL + qpos] = mx - sm * (1.0f / (float)LL);
    } else {
        // ----- vsum: per-(bh,chunk-of-128) column sums of V
        int x = blockIdx.x - 1024;        // [0,512)
        int bhLo = x & 7, r = x >> 3;
        int bhHi = r & 3, c = r >> 2;     // c in [0,16)
        int bh = bhHi * 8 + bhLo;
        int d = tid & 63, sg = tid >> 6;
        size_t base = (size_t)bh * LL * DD;
        int row0 = c * 128 + sg * 32;
        float s = 0.f;
        for (int j = 0; j < 32; ++j) s += V[base + (size_t)(row0 + j) * DD + d];
        __shared__ float part[4][DD];
        part[sg][d] = s;
        __syncthreads();
        if (sg == 0)
            csum[((size_t)bh * 16 + c) * DD + d] = part[0][d] + part[1][d] + part[2][d] + part[3][d];
    }
}

// ---------------------------------------------------------------------------
// Stage 2: blocks [0,512) cumsum V -> out; blocks [512,544) radix top-40 of M.
__global__ __launch_bounds__(256) void stage2_kernel(
        const float* __restrict__ V, const float* __restrict__ csum,
        const float* __restrict__ M, float* __restrict__ out,
        int* __restrict__ topk) {
    int tid = threadIdx.x;
    if (blockIdx.x < 512) {
        // ----- cumsum
        int x = blockIdx.x;
        int bhLo = x & 7, r = x >> 3;
        int bhHi = r & 3, c = r >> 2;
        int bh = bhHi * 8 + bhLo;
        int d = tid & 63, sg = tid >> 6;
        size_t base = (size_t)bh * LL * DD;
        int row0 = c * 128 + sg * 32;
        float v[32];
        #pragma unroll
        for (int j = 0; j < 32; ++j) v[j] = V[base + (size_t)(row0 + j) * DD + d];
        float s = 0.f;
        #pragma unroll
        for (int j = 0; j < 32; ++j) s += v[j];
        __shared__ float part[4][DD];
        part[sg][d] = s;
        __syncthreads();
        float pre = 0.f;
        for (int cc = 0; cc < c; ++cc) pre += csum[((size_t)bh * 16 + cc) * DD + d];
        for (int ss = 0; ss < sg; ++ss) pre += part[ss][d];
        float acc = pre;
        #pragma unroll
        for (int j = 0; j < 32; ++j) {
            acc += v[j];
            out[base + (size_t)(row0 + j) * DD + d] = acc;
        }
    } else {
        // ----- radix top-40 (8 bits/pass, 4 passes); unordered emission.
        int bh = blockIdx.x - 512;
        __shared__ unsigned hist[256];
        __shared__ unsigned bc_prefix, bc_need;
        __shared__ unsigned cnt_gt, cnt_eq;
        __shared__ int eqlist[128];

        unsigned v[8];
        #pragma unroll
        for (int j = 0; j < 8; ++j)
            v[j] = ordu(M[(size_t)bh * LL + tid + j * 256]);

        unsigned prefix = 0, need = SK;
        #pragma unroll
        for (int pass = 0; pass < 4; ++pass) {
            const int s = 24 - 8 * pass;
            const unsigned maskHigh = (pass == 0) ? 0u : (0xFFFFFFFFu << (s + 8));
            hist[tid] = 0;
            __syncthreads();
            #pragma unroll
            for (int j = 0; j < 8; ++j)
                if (((v[j] ^ prefix) & maskHigh) == 0)
                    atomicAdd(&hist[(v[j] >> s) & 0xFF], 1u);
            __syncthreads();
            unsigned above = 0;
            for (int b = tid + 1; b < 256; ++b) above += hist[b];
            if (above < need && above + hist[tid] >= need) {
                bc_prefix = prefix | ((unsigned)tid << s);
                bc_need = need - above;
            }
            __syncthreads();
            prefix = bc_prefix;
            need = bc_need;
            __syncthreads();
        }
        unsigned T = prefix;
        if (tid == 0) { cnt_gt = 0; cnt_eq = 0; }
        __syncthreads();
        #pragma unroll
        for (int j = 0; j < 8; ++j) {
            int idx = tid + j * 256;
            if (v[j] > T) { unsigned p = atomicAdd(&cnt_gt, 1u); topk[bh * SK + p] = idx; }
            else if (v[j] == T) { unsigned p = atomicAdd(&cnt_eq, 1u); if (p < 128) eqlist[p] = idx; }
        }
        __syncthreads();
        if (tid == 0) {
            int ne = (int)min(cnt_eq, 128u);
            unsigned base = cnt_gt;       // == SK - need
            for (unsigned r2 = 0; r2 < need; ++r2) {
                int bj = 0, bv = 0x7FFFFFFF;
                for (int j = 0; j < ne; ++j)
                    if (eqlist[j] < bv) { bv = eqlist[j]; bj = j; }
                topk[bh * SK + base + r2] = bv;
                eqlist[bj] = 0x7FFFFFFF;
            }
        }
    }
}

// ---------------------------------------------------------------------------
// Stage 3: one block per (bh,u): full causal softmax attention over keys
// [0..qpos], overwrite out[bh,qpos,:]. No tiling, no combine.
__global__ __launch_bounds__(256) void attn_kernel(
        const float* __restrict__ Q, const float* __restrict__ K,
        const float* __restrict__ V, const int* __restrict__ topk,
        float* __restrict__ out) {
    int x = blockIdx.x;               // 1280
    int bhLo = x & 7;
    int t = x >> 3;                   // [0,160)
    int u = t % SK;
    int bhHi = t / SK;                // [0,4)
    int bh = bhHi * 8 + bhLo;
    int tid = threadIdx.x;

    int qpos = topk[bh * SK + u];
    int nk = qpos + 1;

    const float4* Q4 = (const float4*)Q;
    const float4* K4 = (const float4*)K;
    const float4* V4 = (const float4*)V;

    int w = tid >> 6, lane = tid & 63;
    int kw = lane >> 2, c = lane & 3;
    float4 qreg[4];
    #pragma unroll
    for (int j = 0; j < 4; ++j)
        qreg[j] = Q4[((size_t)bh * LL + qpos) * 16 + j * 4 + c];

    __shared__ float sc[LL];          // 8 KB
    __shared__ float red[4], red2[4];
    __shared__ float opart[16][16][4];

    // score phase: 4 lanes/key, 64 keys per block-round
    size_t kb4 = (size_t)bh * LL * 16;
    int rounds = (nk + 63) >> 6;
    for (int rr = 0; rr < rounds; ++rr) {
        int key = rr * 64 + w * 16 + kw;
        if (key < nk) {
            const float4* kr = K4 + kb4 + (size_t)key * 16;
            float p = 0.f;
            #pragma unroll
            for (int j = 0; j < 4; ++j) {
                float4 kv = kr[j * 4 + c];
                p += qreg[j].x * kv.x + qreg[j].y * kv.y + qreg[j].z * kv.z + qreg[j].w * kv.w;
            }
            p += __shfl_xor(p, 1, 64);
            p += __shfl_xor(p, 2, 64);
            if (c == 0) sc[key] = p * 0.125f;   // 1/sqrt(64)
        }
    }
    __syncthreads();

    // block max over sc[0..nk)
    float m = -INFINITY;
    for (int j = tid; j < nk; j += 256) m = fmaxf(m, sc[j]);
    #pragma unroll
    for (int off = 32; off > 0; off >>= 1) m = fmaxf(m, __shfl_xor(m, off, 64));
    if (lane == 0) red[w] = m;
    __syncthreads();
    m = fmaxf(fmaxf(red[0], red[1]), fmaxf(red[2], red[3]));

    // exp + block sum
    float ls = 0.f;
    for (int j = tid; j < nk; j += 256) {
        float e = expf(sc[j] - m);
        sc[j] = e;
        ls += e;
    }
    #pragma unroll
    for (int off = 32; off > 0; off >>= 1) ls += __shfl_xor(ls, off, 64);
    if (lane == 0) red2[w] = ls;
    __syncthreads();
    float linv = 1.0f / (red2[0] + red2[1] + red2[2] + red2[3]);

    // weighted V: 16 k-groups x 16 float4 columns
    int col4 = tid & 15, kg = tid >> 4;
    float ax = 0.f, ay = 0.f, az = 0.f, aw = 0.f;
    for (int j = kg; j < nk; j += 16) {
        float sj = sc[j];
        float4 vv = V4[((size_t)bh * LL + j) * 16 + col4];
        ax += sj * vv.x; ay += sj * vv.y; az += sj * vv.z; aw += sj * vv.w;
    }
    opart[kg][col4][0] = ax;
    opart[kg][col4][1] = ay;
    opart[kg][col4][2] = az;
    opart[kg][col4][3] = aw;
    __syncthreads();
    if (tid < DD) {
        int c4 = tid >> 2, cp = tid & 3;
        float s = 0.f;
        #pragma unroll
        for (int kg2 = 0; kg2 < 16; ++kg2) s += opart[kg2][c4][cp];
        out[((size_t)bh * LL + qpos) * DD + tid] = s * linv;
    }
}

// ---------------------------------------------------------------------------
extern "C" void kernel_launch(void* const* d_in, const int* in_sizes, int n_in,
                              void* d_out, int out_size, void* d_ws, size_t ws_size,
                              hipStream_t stream) {
    const float* Q   = (const float*)d_in[0];
    const float* K   = (const float*)d_in[1];
    const float* V   = (const float*)d_in[2];
    const int*   IDX = (const int*)d_in[3];
    float* out = (float*)d_out;

    char* ws = (char*)d_ws;
    float* M    = (float*)ws;  ws += (size_t)BH * LL * sizeof(float);                 // 256 KB
    int*   topk = (int*)ws;    ws += ((size_t)BH * SK * sizeof(int) + 255) & ~255ull;
    float* csum = (float*)ws;  // BH*16*DD floats = 128 KB

    stage1_kernel<<<1536, 256, 0, stream>>>(Q, K, V, IDX, M, csum);
    stage2_kernel<<<544, 256, 0, stream>>>(V, csum, M, out, topk);
    attn_kernel<<<BH * SK, 256, 0, stream>>>(Q, K, V, topk, out);
}